// Round 9
// baseline (277.986 us; speedup 1.0000x reference)
//
#include <hip/hip_runtime.h>
#include <hip/hip_bf16.h>
#include <math.h>

typedef __bf16 bf16;
typedef __attribute__((ext_vector_type(8))) __bf16 bf16x8;
typedef __attribute__((ext_vector_type(4))) __bf16 bf16x4;
typedef __attribute__((ext_vector_type(4))) float f32x4;

#define B_ 2
#define S_ 1024
#define D_ 1024
#define H_ 16
#define HD_ 64
#define F_ 4096
#define M_ 2048
#define DC_ 256
#define NTOK (B_*S_)

__device__ __forceinline__ void gload16(const void* g, void* l) {
    __builtin_amdgcn_global_load_lds(
        (__attribute__((address_space(1))) void*)(void*)(g),
        (__attribute__((address_space(3))) void*)(l), 16, 0, 0);
}

template<int N> __device__ __forceinline__ void wait_vm() {
    if constexpr (N == 0)      asm volatile("s_waitcnt vmcnt(0)" ::: "memory");
    else if constexpr (N == 2) asm volatile("s_waitcnt vmcnt(2)" ::: "memory");
    else if constexpr (N == 4) asm volatile("s_waitcnt vmcnt(4)" ::: "memory");
    else if constexpr (N == 6) asm volatile("s_waitcnt vmcnt(6)" ::: "memory");
    else                       asm volatile("s_waitcnt vmcnt(8)" ::: "memory");
}
__device__ __forceinline__ void wait_lgkm0() {
    asm volatile("s_waitcnt lgkmcnt(0)" ::: "memory");
}
__device__ __forceinline__ float sigm(float x) { return 1.f / (1.f + expf(-x)); }

// ============ MFMA GEMM: C[M,N] = A[M,K] @ Bt[N,K]^T (+resid) ============
// BK=64, depth-2 counted-vmcnt pipeline, XOR-swizzled LDS, XCD chunking over
// 8-row bands walked column-major (needs gridDim.y % 8 == 0).
// EPI 0: normal. EPI 1: dual write f32 Cout + bf16 aux1 (ld 2048).
template<int BM, int BN, bool OUTBF, int EPI>
__global__ __launch_bounds__(256) void mgemm(
    const bf16* __restrict__ A, const bf16* __restrict__ Bt,
    const float* __restrict__ resid, void* __restrict__ Cout,
    int K, int lda, int ldb, int ldc,
    long long sA, long long sB, long long sC,
    void* __restrict__ aux1)
{
    constexpr int WN   = (BM == 128) ? 2 : 4;
    constexpr int WCOL = BN / WN;
    constexpr int FN   = WCOL / 16;
    constexpr int LA = BM * 64, LB = BN * 64;
    constexpr int LPS = BM / 32 + BN / 32;
    __shared__ bf16 lds[2 * (LA + LB)];
    const int z = blockIdx.z;
    A  += (size_t)z * sA;
    Bt += (size_t)z * sB;
    const int gx = gridDim.x;
    const int nwg = gx * gridDim.y;
    const int flat = blockIdx.y * gx + blockIdx.x;
    const int q8 = nwg >> 3, r8 = nwg & 7;
    const int xcd = flat & 7, lid = flat >> 3;
    const int swz = (xcd < r8 ? xcd * (q8 + 1) : r8 * (q8 + 1) + (xcd - r8) * q8) + lid;
    const int band = swz / (8 * gx);
    const int rem  = swz % (8 * gx);
    const int row0 = (band * 8 + (rem & 7)) * BM;
    const int col0 = (rem >> 3) * BN;
    const int tid = threadIdx.x, wid = tid >> 6, lane = tid & 63;
    const int wr = wid / WN, wc = wid % WN;
    const int srow = lane >> 3;
    const int ssub = (lane & 7) ^ (srow & 7);

    f32x4 acc[4][FN];
    #pragma unroll
    for (int m = 0; m < 4; ++m)
        #pragma unroll
        for (int n = 0; n < FN; ++n) acc[m][n] = (f32x4){0.f, 0.f, 0.f, 0.f};

    auto STAGE = [&](int buf, int k0) {
        bf16* Ab = lds + buf * (LA + LB);
        bf16* Bb = Ab + LA;
        #pragma unroll
        for (int i = 0; i < BM / 32; ++i) {
            int c = wid * (BM / 32) + i;
            gload16(A + (size_t)(row0 + c * 8 + srow) * lda + k0 + ssub * 8, Ab + c * 512);
        }
        #pragma unroll
        for (int i = 0; i < BN / 32; ++i) {
            int c = wid * (BN / 32) + i;
            gload16(Bt + (size_t)(col0 + c * 8 + srow) * ldb + k0 + ssub * 8, Bb + c * 512);
        }
    };

    const int nt = K >> 6;
    STAGE(0, 0);
    if (nt > 1) STAGE(1, 64);
    for (int t = 0; t < nt; ++t) {
        if (t < nt - 1) wait_vm<LPS>();
        else            wait_vm<0>();
        __builtin_amdgcn_sched_barrier(0);
        __builtin_amdgcn_s_barrier();
        __builtin_amdgcn_sched_barrier(0);
        const bf16* Ab = lds + (t & 1) * (LA + LB);
        const bf16* Bb = Ab + LA;
        const int ar = wr * 64 + (lane & 15);
        const int br = wc * WCOL + (lane & 15);
        #pragma unroll
        for (int ksel = 0; ksel < 2; ++ksel) {
            const int ps = ((ksel << 2) + (lane >> 4)) ^ (lane & 7);
            bf16x8 af[4], bfr[FN];
            #pragma unroll
            for (int m = 0; m < 4; ++m)
                af[m] = *(const bf16x8*)(Ab + (ar + m * 16) * 64 + ps * 8);
            #pragma unroll
            for (int n = 0; n < FN; ++n)
                bfr[n] = *(const bf16x8*)(Bb + (br + n * 16) * 64 + ps * 8);
            #pragma unroll
            for (int m = 0; m < 4; ++m)
                #pragma unroll
                for (int n = 0; n < FN; ++n)
                    acc[m][n] = __builtin_amdgcn_mfma_f32_16x16x32_bf16(af[m], bfr[n], acc[m][n], 0, 0, 0);
        }
        wait_lgkm0();
        __builtin_amdgcn_sched_barrier(0);
        __builtin_amdgcn_s_barrier();
        __builtin_amdgcn_sched_barrier(0);
        if (t + 2 < nt) STAGE(t & 1, (t + 2) << 6);
    }
    const int crow = row0 + wr * 64 + ((lane >> 4) << 2);
    const int ccol = col0 + wc * WCOL + (lane & 15);
    #pragma unroll
    for (int m = 0; m < 4; ++m)
        #pragma unroll
        for (int n = 0; n < FN; ++n)
            #pragma unroll
            for (int r = 0; r < 4; ++r) {
                const int rr = crow + m * 16 + r, cc = ccol + n * 16;
                size_t idx = (size_t)rr * ldc + cc;
                float v = acc[m][n][r];
                if (resid) v += resid[idx];
                if (OUTBF) ((bf16*)Cout)[(size_t)z * sC + idx] = (bf16)v;
                else       ((float*)Cout)[(size_t)z * sC + idx] = v;
                if (EPI == 1)
                    ((bf16*)aux1)[(size_t)rr * 2048 + cc] = (bf16)v;
            }
}

// ============ Merged gate+proj GEMM ============
// gate = cat[2048,2048] @ WgT^T ; proj = retr(=cat cols 1024..) @ WpjT^T
// h2 = h1 + sigmoid(gate) * proj.  BM=64, BN=64, K=2048; proj accumulates
// only on k>=1024 (same A tile, B3 from WpjT at k-1024).
__global__ __launch_bounds__(256) void mgemm_gp(
    const bf16* __restrict__ A, const bf16* __restrict__ B1t, const bf16* __restrict__ B3t,
    const float* __restrict__ h1, float* __restrict__ h2)
{
    constexpr int LA = 64 * 64, LB = 64 * 64;
    __shared__ bf16 lds[2 * (LA + 2 * LB)];
    const int gx = gridDim.x;
    const int nwg = gx * gridDim.y;
    const int flat = blockIdx.y * gx + blockIdx.x;
    const int q8 = nwg >> 3, r8 = nwg & 7;
    const int xcd = flat & 7, lid = flat >> 3;
    const int swz = (xcd < r8 ? xcd * (q8 + 1) : r8 * (q8 + 1) + (xcd - r8) * q8) + lid;
    const int band = swz / (8 * gx);
    const int rem  = swz % (8 * gx);
    const int row0 = (band * 8 + (rem & 7)) * 64;
    const int col0 = (rem >> 3) * 64;
    const int tid = threadIdx.x, wid = tid >> 6, lane = tid & 63;
    const int wc = wid;                 // WN=4, wr=0
    const int srow = lane >> 3;
    const int ssub = (lane & 7) ^ (srow & 7);

    f32x4 acc1[4], acc3[4];
    #pragma unroll
    for (int m = 0; m < 4; ++m) {
        acc1[m] = (f32x4){0.f, 0.f, 0.f, 0.f};
        acc3[m] = (f32x4){0.f, 0.f, 0.f, 0.f};
    }

    auto STAGE = [&](int buf, int tt) {
        bf16* Ab = lds + buf * (LA + 2 * LB);
        bf16* B1b = Ab + LA;
        bf16* B3b = B1b + LB;
        const int k0 = tt << 6;
        #pragma unroll
        for (int i = 0; i < 2; ++i) {
            int c = wid * 2 + i;
            gload16(A + (size_t)(row0 + c * 8 + srow) * 2048 + k0 + ssub * 8, Ab + c * 512);
        }
        #pragma unroll
        for (int i = 0; i < 2; ++i) {
            int c = wid * 2 + i;
            gload16(B1t + (size_t)(col0 + c * 8 + srow) * 2048 + k0 + ssub * 8, B1b + c * 512);
        }
        if (tt >= 16) {
            const int k3 = (tt - 16) << 6;
            #pragma unroll
            for (int i = 0; i < 2; ++i) {
                int c = wid * 2 + i;
                gload16(B3t + (size_t)(col0 + c * 8 + srow) * 1024 + k3 + ssub * 8, B3b + c * 512);
            }
        }
    };

    STAGE(0, 0);
    STAGE(1, 1);
    for (int t = 0; t < 32; ++t) {
        if (t < 31) { if (t + 1 >= 16) wait_vm<6>(); else wait_vm<4>(); }
        else wait_vm<0>();
        __builtin_amdgcn_sched_barrier(0);
        __builtin_amdgcn_s_barrier();
        __builtin_amdgcn_sched_barrier(0);
        const bf16* Ab = lds + (t & 1) * (LA + 2 * LB);
        const bf16* B1b = Ab + LA;
        const bf16* B3b = B1b + LB;
        const int ar = lane & 15;
        const int br = wc * 16 + (lane & 15);
        #pragma unroll
        for (int ksel = 0; ksel < 2; ++ksel) {
            const int ps = ((ksel << 2) + (lane >> 4)) ^ (lane & 7);
            bf16x8 af[4], b1f, b3f;
            #pragma unroll
            for (int m = 0; m < 4; ++m)
                af[m] = *(const bf16x8*)(Ab + (ar + m * 16) * 64 + ps * 8);
            b1f = *(const bf16x8*)(B1b + br * 64 + ps * 8);
            #pragma unroll
            for (int m = 0; m < 4; ++m)
                acc1[m] = __builtin_amdgcn_mfma_f32_16x16x32_bf16(af[m], b1f, acc1[m], 0, 0, 0);
            if (t >= 16) {
                b3f = *(const bf16x8*)(B3b + br * 64 + ps * 8);
                #pragma unroll
                for (int m = 0; m < 4; ++m)
                    acc3[m] = __builtin_amdgcn_mfma_f32_16x16x32_bf16(af[m], b3f, acc3[m], 0, 0, 0);
            }
        }
        wait_lgkm0();
        __builtin_amdgcn_sched_barrier(0);
        __builtin_amdgcn_s_barrier();
        __builtin_amdgcn_sched_barrier(0);
        if (t + 2 < 32) STAGE(t & 1, t + 2);
    }
    const int crow = row0 + ((lane >> 4) << 2);
    const int ccol = col0 + wc * 16 + (lane & 15);
    #pragma unroll
    for (int m = 0; m < 4; ++m)
        #pragma unroll
        for (int r = 0; r < 4; ++r) {
            size_t idx = (size_t)(crow + m * 16 + r) * 1024 + ccol;
            h2[idx] = h1[idx] + sigm(acc1[m][r]) * acc3[m][r];
        }
}

// ============ Fused MLP-up: a1 = silu(A@W1t^T) * (A@W3t^T), bf16 out ============
__global__ __launch_bounds__(256) void mgemm13(
    const bf16* __restrict__ A, const bf16* __restrict__ B1t, const bf16* __restrict__ B3t,
    bf16* __restrict__ Cout, int K, int lda, int ldb, int ldc)
{
    constexpr int LA = 128 * 64, LB = 64 * 64;
    __shared__ bf16 lds[2 * (LA + 2 * LB)];
    const int gx = gridDim.x;
    const int nwg = gx * gridDim.y;
    const int flat = blockIdx.y * gx + blockIdx.x;
    const int q8 = nwg >> 3, r8 = nwg & 7;
    const int xcd = flat & 7, lid = flat >> 3;
    const int swz = (xcd < r8 ? xcd * (q8 + 1) : r8 * (q8 + 1) + (xcd - r8) * q8) + lid;
    const int band = swz / (8 * gx);
    const int rem  = swz % (8 * gx);
    const int row0 = (band * 8 + (rem & 7)) * 128;
    const int col0 = (rem >> 3) * 64;
    const int tid = threadIdx.x, wid = tid >> 6, lane = tid & 63;
    const int wr = wid >> 1, wc = wid & 1;
    const int srow = lane >> 3;
    const int ssub = (lane & 7) ^ (srow & 7);

    f32x4 acc1[4][2], acc3[4][2];
    #pragma unroll
    for (int m = 0; m < 4; ++m)
        #pragma unroll
        for (int n = 0; n < 2; ++n) {
            acc1[m][n] = (f32x4){0.f, 0.f, 0.f, 0.f};
            acc3[m][n] = (f32x4){0.f, 0.f, 0.f, 0.f};
        }

    auto STAGE = [&](int buf, int k0) {
        bf16* Ab = lds + buf * (LA + 2 * LB);
        bf16* B1b = Ab + LA;
        bf16* B3b = B1b + LB;
        #pragma unroll
        for (int i = 0; i < 4; ++i) {
            int c = wid * 4 + i;
            gload16(A + (size_t)(row0 + c * 8 + srow) * lda + k0 + ssub * 8, Ab + c * 512);
        }
        #pragma unroll
        for (int i = 0; i < 2; ++i) {
            int c = wid * 2 + i;
            gload16(B1t + (size_t)(col0 + c * 8 + srow) * ldb + k0 + ssub * 8, B1b + c * 512);
            gload16(B3t + (size_t)(col0 + c * 8 + srow) * ldb + k0 + ssub * 8, B3b + c * 512);
        }
    };

    const int nt = K >> 6;
    STAGE(0, 0);
    if (nt > 1) STAGE(1, 64);
    for (int t = 0; t < nt; ++t) {
        if (t < nt - 1) wait_vm<8>();
        else            wait_vm<0>();
        __builtin_amdgcn_sched_barrier(0);
        __builtin_amdgcn_s_barrier();
        __builtin_amdgcn_sched_barrier(0);
        const bf16* Ab = lds + (t & 1) * (LA + 2 * LB);
        const bf16* B1b = Ab + LA;
        const bf16* B3b = B1b + LB;
        const int ar = wr * 64 + (lane & 15);
        const int br = wc * 32 + (lane & 15);
        #pragma unroll
        for (int ksel = 0; ksel < 2; ++ksel) {
            const int ps = ((ksel << 2) + (lane >> 4)) ^ (lane & 7);
            bf16x8 af[4], b1f[2], b3f[2];
            #pragma unroll
            for (int m = 0; m < 4; ++m)
                af[m] = *(const bf16x8*)(Ab + (ar + m * 16) * 64 + ps * 8);
            #pragma unroll
            for (int n = 0; n < 2; ++n) {
                b1f[n] = *(const bf16x8*)(B1b + (br + n * 16) * 64 + ps * 8);
                b3f[n] = *(const bf16x8*)(B3b + (br + n * 16) * 64 + ps * 8);
            }
            #pragma unroll
            for (int m = 0; m < 4; ++m)
                #pragma unroll
                for (int n = 0; n < 2; ++n) {
                    acc1[m][n] = __builtin_amdgcn_mfma_f32_16x16x32_bf16(af[m], b1f[n], acc1[m][n], 0, 0, 0);
                    acc3[m][n] = __builtin_amdgcn_mfma_f32_16x16x32_bf16(af[m], b3f[n], acc3[m][n], 0, 0, 0);
                }
        }
        wait_lgkm0();
        __builtin_amdgcn_sched_barrier(0);
        __builtin_amdgcn_s_barrier();
        __builtin_amdgcn_sched_barrier(0);
        if (t + 2 < nt) STAGE(t & 1, (t + 2) << 6);
    }
    const int crow = row0 + wr * 64 + ((lane >> 4) << 2);
    const int ccol = col0 + wc * 32 + (lane & 15);
    #pragma unroll
    for (int m = 0; m < 4; ++m)
        #pragma unroll
        for (int n = 0; n < 2; ++n)
            #pragma unroll
            for (int r = 0; r < 4; ++r) {
                float x = acc1[m][n][r];
                float v = (x * sigm(x)) * acc3[m][n][r];
                Cout[(size_t)(crow + m * 16 + r) * ldc + ccol + n * 16] = (bf16)v;
            }
}

// ============ Fused causal flash attention ============
__global__ __launch_bounds__(256) void flash_attn(
    const bf16* __restrict__ qkv, const bf16* __restrict__ vt,
    bf16* __restrict__ o)
{
    __shared__ bf16 qlds[64 * 64];
    __shared__ bf16 klds[2][64 * 64];
    __shared__ bf16 vlds[2][64 * 64];
    __shared__ bf16 plds[4][16 * 64];
    const int qt = blockIdx.x, hh = blockIdx.y, b = blockIdx.z;
    const int qb0 = qt * 64;
    const int tid = threadIdx.x, wid = tid >> 6, lane = tid & 63;
    const bf16* qg = qkv + (size_t)b * S_ * 3072 + hh * 64;
    const bf16* kg = qg + 1024;
    const bf16* vg = vt + (size_t)(b * H_ + hh) * 64 * 1024;
    const int srow = lane >> 3;
    const int ssub = (lane & 7) ^ (srow & 7);

    #pragma unroll
    for (int i = 0; i < 2; ++i) {
        int c = wid * 2 + i;
        gload16(qg + (size_t)(qb0 + c * 8 + srow) * 3072 + ssub * 8, qlds + c * 512);
    }
    auto STAGE = [&](int buf, int kb) {
        #pragma unroll
        for (int i = 0; i < 2; ++i) {
            int c = wid * 2 + i;
            gload16(kg + (size_t)(kb + c * 8 + srow) * 3072 + ssub * 8, klds[buf] + c * 512);
            gload16(vg + (size_t)(c * 8 + srow) * 1024 + kb + ssub * 8, vlds[buf] + c * 512);
        }
    };

    const int nt = qt + 1;
    STAGE(0, 0);
    if (nt > 1) STAGE(1, 64);

    f32x4 oacc[4];
    #pragma unroll
    for (int n = 0; n < 4; ++n) oacc[n] = (f32x4){0.f, 0.f, 0.f, 0.f};
    float mrow[4] = {-1e30f, -1e30f, -1e30f, -1e30f};
    float lrow[4] = {0.f, 0.f, 0.f, 0.f};
    bf16x8 qf[2];
    bf16* pw = plds[wid];
    const int qlr = (lane >> 4) * 4;

    for (int t = 0; t < nt; ++t) {
        if (t < nt - 1) wait_vm<4>();
        else            wait_vm<0>();
        __builtin_amdgcn_sched_barrier(0);
        __builtin_amdgcn_s_barrier();
        __builtin_amdgcn_sched_barrier(0);
        if (t == 0) {
            const int ar = wid * 16 + (lane & 15);
            #pragma unroll
            for (int ksel = 0; ksel < 2; ++ksel) {
                const int ps = ((ksel << 2) + (lane >> 4)) ^ (lane & 7);
                qf[ksel] = *(const bf16x8*)(qlds + ar * 64 + ps * 8);
            }
        }
        const bf16* Kb = klds[t & 1];
        const bf16* Vb = vlds[t & 1];
        f32x4 sacc[4];
        #pragma unroll
        for (int n = 0; n < 4; ++n) sacc[n] = (f32x4){0.f, 0.f, 0.f, 0.f};
        #pragma unroll
        for (int ksel = 0; ksel < 2; ++ksel) {
            const int ps = ((ksel << 2) + (lane >> 4)) ^ (lane & 7);
            #pragma unroll
            for (int n = 0; n < 4; ++n) {
                bf16x8 kf = *(const bf16x8*)(Kb + (n * 16 + (lane & 15)) * 64 + ps * 8);
                sacc[n] = __builtin_amdgcn_mfma_f32_16x16x32_bf16(qf[ksel], kf, sacc[n], 0, 0, 0);
            }
        }
        if (t == nt - 1) {
            const int qrow = qb0 + wid * 16 + qlr;
            const int kcol = t * 64 + (lane & 15);
            #pragma unroll
            for (int n = 0; n < 4; ++n)
                #pragma unroll
                for (int r = 0; r < 4; ++r)
                    if (kcol + n * 16 > qrow + r) sacc[n][r] = -1e30f;
        }
        #pragma unroll
        for (int r = 0; r < 4; ++r) {
            float mx = fmaxf(fmaxf(sacc[0][r], sacc[1][r]), fmaxf(sacc[2][r], sacc[3][r]));
            #pragma unroll
            for (int off = 8; off > 0; off >>= 1) mx = fmaxf(mx, __shfl_xor(mx, off));
            float mnew = fmaxf(mrow[r], mx);
            float scale = __expf(mrow[r] - mnew);
            float rs = 0.f;
            #pragma unroll
            for (int n = 0; n < 4; ++n) {
                float p = __expf(sacc[n][r] - mnew);
                sacc[n][r] = p;
                rs += p;
            }
            #pragma unroll
            for (int off = 8; off > 0; off >>= 1) rs += __shfl_xor(rs, off);
            lrow[r] = lrow[r] * scale + rs;
            mrow[r] = mnew;
            #pragma unroll
            for (int n = 0; n < 4; ++n) oacc[n][r] *= scale;
        }
        #pragma unroll
        for (int n = 0; n < 4; ++n)
            #pragma unroll
            for (int r = 0; r < 4; ++r) {
                const int qr = qlr + r;
                const int k = n * 16 + (lane & 15);
                const int su = (k >> 3) ^ (qr & 7);
                pw[qr * 64 + su * 8 + (k & 7)] = (bf16)sacc[n][r];
            }
        #pragma unroll
        for (int ksel = 0; ksel < 2; ++ksel) {
            const int ps = ((ksel << 2) + (lane >> 4)) ^ (lane & 7);
            bf16x8 pa = *(const bf16x8*)(pw + (lane & 15) * 64 + ps * 8);
            #pragma unroll
            for (int n = 0; n < 4; ++n) {
                bf16x8 vf = *(const bf16x8*)(Vb + (n * 16 + (lane & 15)) * 64 + ps * 8);
                oacc[n] = __builtin_amdgcn_mfma_f32_16x16x32_bf16(pa, vf, oacc[n], 0, 0, 0);
            }
        }
        wait_lgkm0();
        __builtin_amdgcn_sched_barrier(0);
        __builtin_amdgcn_s_barrier();
        __builtin_amdgcn_sched_barrier(0);
        if (t + 2 < nt) STAGE(t & 1, (t + 2) * 64);
    }
    float inv[4];
    #pragma unroll
    for (int r = 0; r < 4; ++r) inv[r] = 1.f / lrow[r];
    #pragma unroll
    for (int n = 0; n < 4; ++n)
        #pragma unroll
        for (int r = 0; r < 4; ++r) {
            const int q = qb0 + wid * 16 + qlr + r;
            const int d = n * 16 + (lane & 15);
            o[(size_t)(b * S_ + q) * 1024 + hh * 64 + d] = (bf16)(oacc[n][r] * inv[r]);
        }
}

// ============ single mega transpose-cast: all weights ============
struct TCD { const float* src; bf16* dst; int ct; int rt; int start; };
struct TCA { TCD e[12]; };
__global__ __launch_bounds__(256) void tcast_all(TCA p)
{
    __shared__ float t[32][33];
    const int flat = blockIdx.x;
    int i = 0;
    #pragma unroll
    for (int j = 1; j < 12; ++j) if (flat >= p.e[j].start) i = j;
    const TCD d = p.e[i];
    const int local = flat - d.start;
    const int cx = local % d.ct, ry = local / d.ct;
    const int C = d.ct * 32, R = d.rt * 32;
    const int c0 = cx * 32, r0 = ry * 32;
    const int tx = threadIdx.x & 31, ty = threadIdx.x >> 5;
    #pragma unroll
    for (int j = 0; j < 4; ++j)
        t[ty + j * 8][tx] = d.src[(size_t)(r0 + ty + j * 8) * C + c0 + tx];
    __syncthreads();
    #pragma unroll
    for (int j = 0; j < 4; ++j)
        d.dst[(size_t)(c0 + ty + j * 8) * R + r0 + tx] = (bf16)t[tx][ty + j * 8];
}

// ============ RMSNorm -> bf16 out ============
__global__ __launch_bounds__(256) void rmsnorm_bf(
    const float* __restrict__ x, const float* __restrict__ w, bf16* __restrict__ out)
{
    __shared__ float red[4];
    const int row = blockIdx.x, tid = threadIdx.x;
    const float* xr = x + (size_t)row * D_;
    f32x4 v = *(const f32x4*)(xr + tid * 4);
    float ss = v.x * v.x + v.y * v.y + v.z * v.z + v.w * v.w;
    #pragma unroll
    for (int off = 32; off > 0; off >>= 1) ss += __shfl_xor(ss, off);
    if ((tid & 63) == 0) red[tid >> 6] = ss;
    __syncthreads();
    float scn = rsqrtf((red[0] + red[1] + red[2] + red[3]) * (1.f / D_) + 1e-6f);
    f32x4 wv = *(const f32x4*)(w + tid * 4);
    bf16x4 o;
    o[0] = (bf16)(v.x * scn * wv.x); o[1] = (bf16)(v.y * scn * wv.y);
    o[2] = (bf16)(v.z * scn * wv.z); o[3] = (bf16)(v.w * scn * wv.w);
    *(bf16x4*)(out + (size_t)row * D_ + tid * 4) = o;
}

// ============ Fused h1 postlude: strength GEMV + rmsnorm(h1, nmw) ============
__global__ __launch_bounds__(256) void h1_post(
    const float* __restrict__ h1, const float* __restrict__ nmw,
    const float* __restrict__ wst, bf16* __restrict__ nbf, float* __restrict__ stb)
{
    __shared__ float red[4], red2[4];
    const int row = blockIdx.x, tid = threadIdx.x;
    const float* xr = h1 + (size_t)row * D_;
    f32x4 v = *(const f32x4*)(xr + tid * 4);
    f32x4 wv = *(const f32x4*)(wst + tid * 4);
    float ss = v.x * v.x + v.y * v.y + v.z * v.z + v.w * v.w;
    float dt = v.x * wv.x + v.y * wv.y + v.z * wv.z + v.w * wv.w;
    #pragma unroll
    for (int off = 32; off > 0; off >>= 1) {
        ss += __shfl_xor(ss, off);
        dt += __shfl_xor(dt, off);
    }
    if ((tid & 63) == 0) { red[tid >> 6] = ss; red2[tid >> 6] = dt; }
    __syncthreads();
    float scn = rsqrtf((red[0] + red[1] + red[2] + red[3]) * (1.f / D_) + 1e-6f);
    f32x4 nw = *(const f32x4*)(nmw + tid * 4);
    bf16x4 o;
    o[0] = (bf16)(v.x * scn * nw.x); o[1] = (bf16)(v.y * scn * nw.y);
    o[2] = (bf16)(v.z * scn * nw.z); o[3] = (bf16)(v.w * scn * nw.w);
    *(bf16x4*)(nbf + (size_t)row * D_ + tid * 4) = o;
    if (tid == 0) stb[row] = sigm(red2[0] + red2[1] + red2[2] + red2[3]);
}

// ============ Fused RoPE (q,k in-place) + V^T staging ============
__global__ __launch_bounds__(256) void rope_vt(
    bf16* __restrict__ qkv, const float* __restrict__ cosp,
    const float* __restrict__ sinp, bf16* __restrict__ vt)
{
    __shared__ bf16 vl[64][72];
    const int st = blockIdx.x, hh = blockIdx.y, b = blockIdx.z;
    const int tid = threadIdx.x;
    const int r = tid >> 2;
    const int p0 = (tid & 3) * 8;
    const int s = st * 64 + r;
    bf16* base = qkv + ((size_t)(b * S_ + s)) * 3072 + hh * 64;
    {
        f32x4 c1a = *(const f32x4*)(cosp + s * 64 + p0);
        f32x4 c1b = *(const f32x4*)(cosp + s * 64 + p0 + 4);
        f32x4 s1a = *(const f32x4*)(sinp + s * 64 + p0);
        f32x4 s1b = *(const f32x4*)(sinp + s * 64 + p0 + 4);
        f32x4 c2a = *(const f32x4*)(cosp + s * 64 + p0 + 32);
        f32x4 c2b = *(const f32x4*)(cosp + s * 64 + p0 + 36);
        f32x4 s2a = *(const f32x4*)(sinp + s * 64 + p0 + 32);
        f32x4 s2b = *(const f32x4*)(sinp + s * 64 + p0 + 36);
        float c1[8] = {c1a.x,c1a.y,c1a.z,c1a.w,c1b.x,c1b.y,c1b.z,c1b.w};
        float s1[8] = {s1a.x,s1a.y,s1a.z,s1a.w,s1b.x,s1b.y,s1b.z,s1b.w};
        float c2[8] = {c2a.x,c2a.y,c2a.z,c2a.w,c2b.x,c2b.y,c2b.z,c2b.w};
        float s2[8] = {s2a.x,s2a.y,s2a.z,s2a.w,s2b.x,s2b.y,s2b.z,s2b.w};
        #pragma unroll
        for (int which = 0; which < 2; ++which) {
            bf16* ptr = base + which * 1024;
            bf16x8 x1 = *(const bf16x8*)(ptr + p0);
            bf16x8 x2 = *(const bf16x8*)(ptr + p0 + 32);
            bf16x8 o1, o2;
            float qs = which ? 1.f : 0.125f;
            #pragma unroll
            for (int j = 0; j < 8; ++j) {
                float a = (float)x1[j], bb = (float)x2[j];
                o1[j] = (bf16)((a * c1[j] - bb * s1[j]) * qs);
                o2[j] = (bf16)((bb * c2[j] + a * s2[j]) * qs);
            }
            *(bf16x8*)(ptr + p0) = o1;
            *(bf16x8*)(ptr + p0 + 32) = o2;
        }
    }
    {
        const int d0 = (tid & 3) * 16;
        bf16x8 v0 = *(const bf16x8*)(base + 2048 + d0);
        bf16x8 v1 = *(const bf16x8*)(base + 2048 + d0 + 8);
        #pragma unroll
        for (int j = 0; j < 8; ++j) { vl[r][d0 + j] = v0[j]; vl[r][d0 + 8 + j] = v1[j]; }
    }
    __syncthreads();
    {
        const int d = tid >> 2;
        const int sq = (tid & 3) * 16;
        bf16x8 o0, o1;
        #pragma unroll
        for (int j = 0; j < 8; ++j) { o0[j] = vl[sq + j][d]; o1[j] = vl[sq + 8 + j][d]; }
        bf16* dst = vt + (size_t)(b * H_ + hh) * 65536 + (size_t)d * 1024 + st * 64 + sq;
        *(bf16x8*)(dst) = o0;
        *(bf16x8*)(dst + 8) = o1;
    }
}

// ============ memory softmax: bf16 [row][2048] -> bf16 probs, scale 1/16 ============
__global__ __launch_bounds__(256) void mem_softmax(
    const bf16* __restrict__ ms, bf16* __restrict__ out)
{
    __shared__ float red[4];
    const int row = blockIdx.x, tid = threadIdx.x;
    bf16x8 iv = *(const bf16x8*)(ms + (size_t)row * 2048 + tid * 8);
    float xs[8];
    float mx = -1e30f;
    #pragma unroll
    for (int i = 0; i < 8; ++i) { xs[i] = (float)iv[i]; mx = fmaxf(mx, xs[i]); }
    #pragma unroll
    for (int off = 32; off > 0; off >>= 1) mx = fmaxf(mx, __shfl_xor(mx, off));
    if ((tid & 63) == 0) red[tid >> 6] = mx;
    __syncthreads();
    mx = fmaxf(fmaxf(red[0], red[1]), fmaxf(red[2], red[3]));
    __syncthreads();
    float sum = 0.f;
    #pragma unroll
    for (int i = 0; i < 8; ++i) { xs[i] = __expf((xs[i] - mx) * 0.0625f); sum += xs[i]; }
    #pragma unroll
    for (int off = 32; off > 0; off >>= 1) sum += __shfl_xor(sum, off);
    if ((tid & 63) == 0) red[tid >> 6] = sum;
    __syncthreads();
    float inv = 1.f / (red[0] + red[1] + red[2] + red[3]);
    bf16x8 o;
    #pragma unroll
    for (int i = 0; i < 8; ++i) o[i] = (bf16)(xs[i] * inv);
    *(bf16x8*)(out + (size_t)row * 2048 + tid * 8) = o;
}

// ============ memory update + new_values^T in one pass ============
__global__ __launch_bounds__(256) void mem_upd2(
    const bf16* __restrict__ ctcp, const float* __restrict__ st,
    const float* __restrict__ memk, const float* __restrict__ memv,
    const int* __restrict__ pos,
    float* __restrict__ outk, float* __restrict__ outv,
    bf16* __restrict__ okbf, bf16* __restrict__ nvt)
{
    __shared__ float tl[64][65];
    const int dt = blockIdx.x, mt = blockIdx.y, b = blockIdx.z;
    const int tid = threadIdx.x;
    const int r = tid >> 2, q = tid & 3;
    const int m = mt * 64 + r;
    int s = (m - pos[0]) % M_; if (s < 0) s += M_;
    const bool upd = (s < S_);
    const float t = upd ? st[b * S_ + s] : 0.f;
    float res[16];
    if (dt < 16) {
        const int c0 = dt * 64 + q * 16;
        size_t vi = ((size_t)b * M_ + m) * D_ + c0;
        #pragma unroll
        for (int j = 0; j < 4; ++j) {
            f32x4 o = *(const f32x4*)(memv + vi + j * 4);
            res[4*j] = o.x; res[4*j+1] = o.y; res[4*j+2] = o.z; res[4*j+3] = o.w;
        }
        if (upd) {
            const bf16* cp = ctcp + ((size_t)(b * S_ + s)) * 1280 + c0;
            bf16x8 ca = *(const bf16x8*)cp;
            bf16x8 cb = *(const bf16x8*)(cp + 8);
            #pragma unroll
            for (int j = 0; j < 8; ++j) {
                res[j]     = t * (float)ca[j] + (1.f - t) * res[j];
                res[8 + j] = t * (float)cb[j] + (1.f - t) * res[8 + j];
            }
        }
        #pragma unroll
        for (int j = 0; j < 4; ++j) {
            f32x4 o = {res[4*j], res[4*j+1], res[4*j+2], res[4*j+3]};
            *(f32x4*)(outv + vi + j * 4) = o;
        }
        #pragma unroll
        for (int j = 0; j < 16; ++j) tl[r][q * 16 + j] = res[j];
        __syncthreads();
        const int rd = tid >> 2;
        bf16x8 oa, ob;
        #pragma unroll
        for (int j = 0; j < 8; ++j) {
            oa[j] = (bf16)tl[q * 16 + j][rd];
            ob[j] = (bf16)tl[q * 16 + 8 + j][rd];
        }
        bf16* dst = nvt + (size_t)b * 1024 * 2048 + (size_t)(dt * 64 + rd) * 2048 + mt * 64 + q * 16;
        *(bf16x8*)dst = oa;
        *(bf16x8*)(dst + 8) = ob;
    } else {
        const int c0 = (dt - 16) * 64 + q * 16;
        size_t ki = ((size_t)b * M_ + m) * DC_ + c0;
        #pragma unroll
        for (int j = 0; j < 4; ++j) {
            f32x4 o = *(const f32x4*)(memk + ki + j * 4);
            res[4*j] = o.x; res[4*j+1] = o.y; res[4*j+2] = o.z; res[4*j+3] = o.w;
        }
        if (upd) {
            const bf16* cp = ctcp + ((size_t)(b * S_ + s)) * 1280 + 1024 + c0;
            bf16x8 ca = *(const bf16x8*)cp;
            bf16x8 cb = *(const bf16x8*)(cp + 8);
            #pragma unroll
            for (int j = 0; j < 8; ++j) {
                res[j]     = t * (float)ca[j] + (1.f - t) * res[j];
                res[8 + j] = t * (float)cb[j] + (1.f - t) * res[8 + j];
            }
        }
        bf16x8 oa, ob;
        #pragma unroll
        for (int j = 0; j < 4; ++j) {
            f32x4 o = {res[4*j], res[4*j+1], res[4*j+2], res[4*j+3]};
            *(f32x4*)(outk + ki + j * 4) = o;
        }
        #pragma unroll
        for (int j = 0; j < 8; ++j) { oa[j] = (bf16)res[j]; ob[j] = (bf16)res[8 + j]; }
        *(bf16x8*)(okbf + ki) = oa;
        *(bf16x8*)(okbf + ki + 8) = ob;
    }
}

extern "C" void kernel_launch(void* const* d_in, const int* in_sizes, int n_in,
                              void* d_out, int out_size, void* d_ws, size_t ws_size,
                              hipStream_t stream)
{
    const float* h0   = (const float*)d_in[0];
    const float* memk = (const float*)d_in[1];
    const float* memv = (const float*)d_in[2];
    const float* cosp = (const float*)d_in[3];
    const float* sinp = (const float*)d_in[4];
    const float* n1w  = (const float*)d_in[5];
    const float* n2w  = (const float*)d_in[6];
    const float* nmw  = (const float*)d_in[7];
    const float* Wq   = (const float*)d_in[8];
    const float* Wk   = (const float*)d_in[9];
    const float* Wv   = (const float*)d_in[10];
    const float* Wo   = (const float*)d_in[11];
    const float* Wct  = (const float*)d_in[12];
    const float* Wcp  = (const float*)d_in[13];
    const float* Wst  = (const float*)d_in[14];
    const float* Wqr  = (const float*)d_in[15];
    const float* Wg   = (const float*)d_in[16];
    const float* Wpj  = (const float*)d_in[17];
    const float* W1   = (const float*)d_in[18];
    const float* W3   = (const float*)d_in[19];
    const float* W2   = (const float*)d_in[20];
    const int*   pos  = (const int*)d_in[21];

    float* out_h = (float*)d_out;
    float* out_k = out_h + (size_t)NTOK * D_;
    float* out_v = out_k + (size_t)B_ * M_ * DC_;

    char* W = (char*)d_ws;
    const size_t MB = 1u << 20;
    bf16*  qkvb = (bf16*)(W);               // 0..12 MB [2048][3072]
    bf16*  vtb  = (bf16*)(W + 12 * MB);     // 12..16 V^T
    bf16*  nbf  = (bf16*)(W + 16 * MB);     // 16..20 rmsnorm out
    bf16*  abf  = (bf16*)(W + 20 * MB);     // 20..24 attn out
    float* h1b  = (float*)(W + 24 * MB);    // 24..32
    bf16*  catbf= (bf16*)(W + 32 * MB);     // 32..40 [2048][2048] = [h1bf | retr]
    bf16*  ctcp = (bf16*)(W + 40 * MB);     // 40..45 bf16 [2048][1280]
    float* stb  = (float*)(W + 51 * MB);    // 8 KB
    bf16*  msbf = (bf16*)(W + 52 * MB);     // 52..60 mem scores bf16
    bf16*  matt = (bf16*)(W + 68 * MB);     // 68..76 mem probs
    bf16*  nvt  = (bf16*)(W + 76 * MB);     // 76..84 new_values^T
    bf16*  a1bf = (bf16*)(W);               // 0..16 MLP act (overlays qkvb+vtb)
    bf16*  okbf = (bf16*)(W + 84 * MB);     // 84..86
    bf16*  qmbf = (bf16*)(W + 86 * MB);     // 86..87
    float* h2b  = (float*)(W + 96 * MB);    // 96..104
    bf16*  WqkvT= (bf16*)(W + 104 * MB);    // 104..110
    bf16*  WoT  = (bf16*)(W + 110 * MB);    // 110..112
    bf16*  WctcpT=(bf16*)(W + 112 * MB);    // 112..114.5
    bf16*  WqrT = (bf16*)(W + 115 * MB);    // 115..115.5
    bf16*  WgT  = (bf16*)(W + 116 * MB);    // 116..120
    bf16*  WpjT = (bf16*)(W + 120 * MB);    // 120..122
    bf16*  W13T = (bf16*)(W + 122 * MB);    // 122..138
    bf16*  W2T  = (bf16*)(W + 138 * MB);    // 138..146

    // ---- single mega weight transpose-cast ----
    {
        TCA p;
        auto set = [&](int i, const float* s, bf16* d, int ct, int rt, int st_) {
            p.e[i].src = s; p.e[i].dst = d; p.e[i].ct = ct; p.e[i].rt = rt; p.e[i].start = st_;
        };
        int off = 0;
        set(0,  Wq,  WqkvT,               32, 32,  off); off += 1024;
        set(1,  Wk,  WqkvT + 1024 * 1024, 32, 32,  off); off += 1024;
        set(2,  Wv,  WqkvT + 2048 * 1024, 32, 32,  off); off += 1024;
        set(3,  Wo,  WoT,                 32, 32,  off); off += 1024;
        set(4,  Wct, WctcpT,              32, 32,  off); off += 1024;
        set(5,  Wpj, WpjT,                32, 32,  off); off += 1024;
        set(6,  Wcp, WctcpT + 1024 * 1024, 8, 32,  off); off += 256;
        set(7,  Wqr, WqrT,                 8, 32,  off); off += 256;
        set(8,  Wg,  WgT,                 32, 64,  off); off += 2048;
        set(9,  W1,  W13T,               128, 32,  off); off += 4096;
        set(10, W3,  W13T + 4096 * 1024, 128, 32,  off); off += 4096;
        set(11, W2,  W2T,                 32, 128, off); off += 4096;
        tcast_all<<<off, 256, 0, stream>>>(p);
    }

    // ---- 1. rmsnorm; QKV (128x128 tiles); fused RoPE + V^T ----
    rmsnorm_bf<<<NTOK, 256, 0, stream>>>(h0, n1w, nbf);
    mgemm<128, 128, true, 0><<<dim3(24, 16, 1), 256, 0, stream>>>(
        nbf, WqkvT, nullptr, qkvb, 1024, 1024, 1024, 3072, 0, 0, 0, nullptr);
    rope_vt<<<dim3(S_ / 64, H_, B_), 256, 0, stream>>>(qkvb, cosp, sinp, vtb);

    // ---- 2. fused causal flash attention ----
    flash_attn<<<dim3(S_ / 64, H_, B_), 256, 0, stream>>>(qkvb, vtb, abf);

    // ---- 3. h1 = h0 + attn @ Wo (128x64, dual write) + fused strength/rmsnorm ----
    mgemm<128, 64, false, 1><<<dim3(16, 16, 1), 256, 0, stream>>>(
        abf, WoT, h0, h1b, 1024, 1024, 1024, 1024, 0, 0, 0, catbf);
    h1_post<<<NTOK, 256, 0, stream>>>(h1b, nmw, Wst, nbf, stb);

    // ---- 4. content|compressed (128x64, bf16); memory update + nvt ----
    mgemm<128, 64, true, 0><<<dim3(20, 16, 1), 256, 0, stream>>>(
        catbf, WctcpT, nullptr, ctcp, 1024, 2048, 1024, 1280, 0, 0, 0, nullptr);
    mem_upd2<<<dim3(20, 32, 2), 256, 0, stream>>>(
        ctcp, stb, memk, memv, pos, out_k, out_v, okbf, nvt);

    // ---- 5. memory attention ----
    mgemm<64, 64, true, 0><<<dim3(4, 32, 1), 256, 0, stream>>>(
        nbf, WqrT, nullptr, qmbf, 1024, 1024, 1024, 256, 0, 0, 0, nullptr);
    mgemm<128, 64, true, 0><<<dim3(32, 8, 2), 256, 0, stream>>>(
        qmbf, okbf, nullptr, msbf, 256, 256, 256, 2048,
        (long long)S_ * 256, (long long)M_ * 256, (long long)S_ * 2048, nullptr);
    mem_softmax<<<NTOK, 256, 0, stream>>>(msbf, matt);
    mgemm<128, 64, true, 0><<<dim3(16, 8, 2), 256, 0, stream>>>(
        matt, nvt, nullptr, catbf + 1024, 2048, 2048, 2048, 2048,
        (long long)S_ * 2048, (long long)1024 * 2048, (long long)S_ * 2048, nullptr);

    // ---- 6. merged gate+proj GEMM with sigmoid-gate combine ----
    mgemm_gp<<<dim3(16, 32, 1), 256, 0, stream>>>(catbf, WgT, WpjT, h1b, h2b);

    // ---- 7. MLP (fused up+silu-mul, then down 128x64) ----
    rmsnorm_bf<<<NTOK, 256, 0, stream>>>(h2b, n2w, nbf);
    mgemm13<<<dim3(64, 16, 1), 256, 0, stream>>>(
        nbf, W13T, W13T + 4096 * 1024, a1bf, 1024, 1024, 1024, 4096);
    mgemm<128, 64, false, 0><<<dim3(16, 16, 1), 256, 0, stream>>>(
        a1bf, W2T, h2b, out_h, 4096, 4096, 4096, 1024, 0, 0, 0, nullptr);
}

// Round 10
// 274.269 us; speedup vs baseline: 1.0136x; 1.0136x over previous
//
#include <hip/hip_runtime.h>
#include <hip/hip_bf16.h>
#include <math.h>

typedef __bf16 bf16;
typedef __attribute__((ext_vector_type(8))) __bf16 bf16x8;
typedef __attribute__((ext_vector_type(4))) __bf16 bf16x4;
typedef __attribute__((ext_vector_type(4))) float f32x4;

#define B_ 2
#define S_ 1024
#define D_ 1024
#define H_ 16
#define HD_ 64
#define F_ 4096
#define M_ 2048
#define DC_ 256
#define NTOK (B_*S_)

__device__ __forceinline__ void gload16(const void* g, void* l) {
    __builtin_amdgcn_global_load_lds(
        (__attribute__((address_space(1))) void*)(void*)(g),
        (__attribute__((address_space(3))) void*)(l), 16, 0, 0);
}

template<int N> __device__ __forceinline__ void wait_vm() {
    if constexpr (N == 0)      asm volatile("s_waitcnt vmcnt(0)" ::: "memory");
    else if constexpr (N == 2) asm volatile("s_waitcnt vmcnt(2)" ::: "memory");
    else if constexpr (N == 4) asm volatile("s_waitcnt vmcnt(4)" ::: "memory");
    else if constexpr (N == 6) asm volatile("s_waitcnt vmcnt(6)" ::: "memory");
    else                       asm volatile("s_waitcnt vmcnt(8)" ::: "memory");
}
__device__ __forceinline__ void wait_lgkm0() {
    asm volatile("s_waitcnt lgkmcnt(0)" ::: "memory");
}
__device__ __forceinline__ float sigm(float x) { return 1.f / (1.f + expf(-x)); }

// ============ MFMA GEMM: C[M,N] = A[M,K] @ Bt[N,K]^T (+resid) ============
// BK=64, depth-2 counted-vmcnt pipeline, XOR-swizzled LDS, XCD chunking over
// 8-row bands walked column-major (needs gridDim.y % 8 == 0).
// EPI 0: normal. EPI 1: dual write f32 Cout + bf16 aux1 (ld 2048).
// EPI 3: split-K partial — atomicAdd f32 into Cout (Cout pre-filled upstream).
template<int BM, int BN, bool OUTBF, int EPI>
__global__ __launch_bounds__(256) void mgemm(
    const bf16* __restrict__ A, const bf16* __restrict__ Bt,
    const float* __restrict__ resid, void* __restrict__ Cout,
    int K, int lda, int ldb, int ldc,
    long long sA, long long sB, long long sC,
    void* __restrict__ aux1)
{
    constexpr int WN   = (BM == 128) ? 2 : 4;
    constexpr int WCOL = BN / WN;
    constexpr int FN   = WCOL / 16;
    constexpr int LA = BM * 64, LB = BN * 64;
    constexpr int LPS = BM / 32 + BN / 32;
    __shared__ bf16 lds[2 * (LA + LB)];
    const int z = blockIdx.z;
    A  += (size_t)z * sA;
    Bt += (size_t)z * sB;
    const int gx = gridDim.x;
    const int nwg = gx * gridDim.y;
    const int flat = blockIdx.y * gx + blockIdx.x;
    const int q8 = nwg >> 3, r8 = nwg & 7;
    const int xcd = flat & 7, lid = flat >> 3;
    const int swz = (xcd < r8 ? xcd * (q8 + 1) : r8 * (q8 + 1) + (xcd - r8) * q8) + lid;
    const int band = swz / (8 * gx);
    const int rem  = swz % (8 * gx);
    const int row0 = (band * 8 + (rem & 7)) * BM;
    const int col0 = (rem >> 3) * BN;
    const int tid = threadIdx.x, wid = tid >> 6, lane = tid & 63;
    const int wr = wid / WN, wc = wid % WN;
    const int srow = lane >> 3;
    const int ssub = (lane & 7) ^ (srow & 7);

    f32x4 acc[4][FN];
    #pragma unroll
    for (int m = 0; m < 4; ++m)
        #pragma unroll
        for (int n = 0; n < FN; ++n) acc[m][n] = (f32x4){0.f, 0.f, 0.f, 0.f};

    auto STAGE = [&](int buf, int k0) {
        bf16* Ab = lds + buf * (LA + LB);
        bf16* Bb = Ab + LA;
        #pragma unroll
        for (int i = 0; i < BM / 32; ++i) {
            int c = wid * (BM / 32) + i;
            gload16(A + (size_t)(row0 + c * 8 + srow) * lda + k0 + ssub * 8, Ab + c * 512);
        }
        #pragma unroll
        for (int i = 0; i < BN / 32; ++i) {
            int c = wid * (BN / 32) + i;
            gload16(Bt + (size_t)(col0 + c * 8 + srow) * ldb + k0 + ssub * 8, Bb + c * 512);
        }
    };

    const int nt = K >> 6;
    STAGE(0, 0);
    if (nt > 1) STAGE(1, 64);
    for (int t = 0; t < nt; ++t) {
        if (t < nt - 1) wait_vm<LPS>();
        else            wait_vm<0>();
        __builtin_amdgcn_sched_barrier(0);
        __builtin_amdgcn_s_barrier();
        __builtin_amdgcn_sched_barrier(0);
        const bf16* Ab = lds + (t & 1) * (LA + LB);
        const bf16* Bb = Ab + LA;
        const int ar = wr * 64 + (lane & 15);
        const int br = wc * WCOL + (lane & 15);
        #pragma unroll
        for (int ksel = 0; ksel < 2; ++ksel) {
            const int ps = ((ksel << 2) + (lane >> 4)) ^ (lane & 7);
            bf16x8 af[4], bfr[FN];
            #pragma unroll
            for (int m = 0; m < 4; ++m)
                af[m] = *(const bf16x8*)(Ab + (ar + m * 16) * 64 + ps * 8);
            #pragma unroll
            for (int n = 0; n < FN; ++n)
                bfr[n] = *(const bf16x8*)(Bb + (br + n * 16) * 64 + ps * 8);
            #pragma unroll
            for (int m = 0; m < 4; ++m)
                #pragma unroll
                for (int n = 0; n < FN; ++n)
                    acc[m][n] = __builtin_amdgcn_mfma_f32_16x16x32_bf16(af[m], bfr[n], acc[m][n], 0, 0, 0);
        }
        wait_lgkm0();
        __builtin_amdgcn_sched_barrier(0);
        __builtin_amdgcn_s_barrier();
        __builtin_amdgcn_sched_barrier(0);
        if (t + 2 < nt) STAGE(t & 1, (t + 2) << 6);
    }
    const int crow = row0 + wr * 64 + ((lane >> 4) << 2);
    const int ccol = col0 + wc * WCOL + (lane & 15);
    #pragma unroll
    for (int m = 0; m < 4; ++m)
        #pragma unroll
        for (int n = 0; n < FN; ++n)
            #pragma unroll
            for (int r = 0; r < 4; ++r) {
                const int rr = crow + m * 16 + r, cc = ccol + n * 16;
                size_t idx = (size_t)rr * ldc + cc;
                float v = acc[m][n][r];
                if (EPI == 3) {
                    atomicAdd(&((float*)Cout)[idx], v);
                } else {
                    if (resid) v += resid[idx];
                    if (OUTBF) ((bf16*)Cout)[(size_t)z * sC + idx] = (bf16)v;
                    else       ((float*)Cout)[(size_t)z * sC + idx] = v;
                    if (EPI == 1)
                        ((bf16*)aux1)[(size_t)rr * 2048 + cc] = (bf16)v;
                }
            }
}

// ============ Merged gate+proj GEMM ============
// gate = cat[2048,2048] @ WgT^T ; proj = retr(=cat cols 1024..) @ WpjT^T
// h2 = h1 + sigmoid(gate) * proj; dual-writes h2 to f32 h2b AND out_h
// (out_h prefill for the split-K W2 atomicAdd that follows).
__global__ __launch_bounds__(256) void mgemm_gp(
    const bf16* __restrict__ A, const bf16* __restrict__ B1t, const bf16* __restrict__ B3t,
    const float* __restrict__ h1, float* __restrict__ h2, float* __restrict__ outh)
{
    constexpr int LA = 64 * 64, LB = 64 * 64;
    __shared__ bf16 lds[2 * (LA + 2 * LB)];
    const int gx = gridDim.x;
    const int nwg = gx * gridDim.y;
    const int flat = blockIdx.y * gx + blockIdx.x;
    const int q8 = nwg >> 3, r8 = nwg & 7;
    const int xcd = flat & 7, lid = flat >> 3;
    const int swz = (xcd < r8 ? xcd * (q8 + 1) : r8 * (q8 + 1) + (xcd - r8) * q8) + lid;
    const int band = swz / (8 * gx);
    const int rem  = swz % (8 * gx);
    const int row0 = (band * 8 + (rem & 7)) * 64;
    const int col0 = (rem >> 3) * 64;
    const int tid = threadIdx.x, wid = tid >> 6, lane = tid & 63;
    const int wc = wid;                 // WN=4, wr=0
    const int srow = lane >> 3;
    const int ssub = (lane & 7) ^ (srow & 7);

    f32x4 acc1[4], acc3[4];
    #pragma unroll
    for (int m = 0; m < 4; ++m) {
        acc1[m] = (f32x4){0.f, 0.f, 0.f, 0.f};
        acc3[m] = (f32x4){0.f, 0.f, 0.f, 0.f};
    }

    auto STAGE = [&](int buf, int tt) {
        bf16* Ab = lds + buf * (LA + 2 * LB);
        bf16* B1b = Ab + LA;
        bf16* B3b = B1b + LB;
        const int k0 = tt << 6;
        #pragma unroll
        for (int i = 0; i < 2; ++i) {
            int c = wid * 2 + i;
            gload16(A + (size_t)(row0 + c * 8 + srow) * 2048 + k0 + ssub * 8, Ab + c * 512);
        }
        #pragma unroll
        for (int i = 0; i < 2; ++i) {
            int c = wid * 2 + i;
            gload16(B1t + (size_t)(col0 + c * 8 + srow) * 2048 + k0 + ssub * 8, B1b + c * 512);
        }
        if (tt >= 16) {
            const int k3 = (tt - 16) << 6;
            #pragma unroll
            for (int i = 0; i < 2; ++i) {
                int c = wid * 2 + i;
                gload16(B3t + (size_t)(col0 + c * 8 + srow) * 1024 + k3 + ssub * 8, B3b + c * 512);
            }
        }
    };

    STAGE(0, 0);
    STAGE(1, 1);
    for (int t = 0; t < 32; ++t) {
        if (t < 31) { if (t + 1 >= 16) wait_vm<6>(); else wait_vm<4>(); }
        else wait_vm<0>();
        __builtin_amdgcn_sched_barrier(0);
        __builtin_amdgcn_s_barrier();
        __builtin_amdgcn_sched_barrier(0);
        const bf16* Ab = lds + (t & 1) * (LA + 2 * LB);
        const bf16* B1b = Ab + LA;
        const bf16* B3b = B1b + LB;
        const int ar = lane & 15;
        const int br = wc * 16 + (lane & 15);
        #pragma unroll
        for (int ksel = 0; ksel < 2; ++ksel) {
            const int ps = ((ksel << 2) + (lane >> 4)) ^ (lane & 7);
            bf16x8 af[4], b1f, b3f;
            #pragma unroll
            for (int m = 0; m < 4; ++m)
                af[m] = *(const bf16x8*)(Ab + (ar + m * 16) * 64 + ps * 8);
            b1f = *(const bf16x8*)(B1b + br * 64 + ps * 8);
            #pragma unroll
            for (int m = 0; m < 4; ++m)
                acc1[m] = __builtin_amdgcn_mfma_f32_16x16x32_bf16(af[m], b1f, acc1[m], 0, 0, 0);
            if (t >= 16) {
                b3f = *(const bf16x8*)(B3b + br * 64 + ps * 8);
                #pragma unroll
                for (int m = 0; m < 4; ++m)
                    acc3[m] = __builtin_amdgcn_mfma_f32_16x16x32_bf16(af[m], b3f, acc3[m], 0, 0, 0);
            }
        }
        wait_lgkm0();
        __builtin_amdgcn_sched_barrier(0);
        __builtin_amdgcn_s_barrier();
        __builtin_amdgcn_sched_barrier(0);
        if (t + 2 < 32) STAGE(t & 1, t + 2);
    }
    const int crow = row0 + ((lane >> 4) << 2);
    const int ccol = col0 + wc * 16 + (lane & 15);
    #pragma unroll
    for (int m = 0; m < 4; ++m)
        #pragma unroll
        for (int r = 0; r < 4; ++r) {
            size_t idx = (size_t)(crow + m * 16 + r) * 1024 + ccol;
            float v = h1[idx] + sigm(acc1[m][r]) * acc3[m][r];
            h2[idx] = v;
            outh[idx] = v;
        }
}

// ============ Fused MLP-up: a1 = silu(A@W1t^T) * (A@W3t^T), bf16 out ============
__global__ __launch_bounds__(256) void mgemm13(
    const bf16* __restrict__ A, const bf16* __restrict__ B1t, const bf16* __restrict__ B3t,
    bf16* __restrict__ Cout, int K, int lda, int ldb, int ldc)
{
    constexpr int LA = 128 * 64, LB = 64 * 64;
    __shared__ bf16 lds[2 * (LA + 2 * LB)];
    const int gx = gridDim.x;
    const int nwg = gx * gridDim.y;
    const int flat = blockIdx.y * gx + blockIdx.x;
    const int q8 = nwg >> 3, r8 = nwg & 7;
    const int xcd = flat & 7, lid = flat >> 3;
    const int swz = (xcd < r8 ? xcd * (q8 + 1) : r8 * (q8 + 1) + (xcd - r8) * q8) + lid;
    const int band = swz / (8 * gx);
    const int rem  = swz % (8 * gx);
    const int row0 = (band * 8 + (rem & 7)) * 128;
    const int col0 = (rem >> 3) * 64;
    const int tid = threadIdx.x, wid = tid >> 6, lane = tid & 63;
    const int wr = wid >> 1, wc = wid & 1;
    const int srow = lane >> 3;
    const int ssub = (lane & 7) ^ (srow & 7);

    f32x4 acc1[4][2], acc3[4][2];
    #pragma unroll
    for (int m = 0; m < 4; ++m)
        #pragma unroll
        for (int n = 0; n < 2; ++n) {
            acc1[m][n] = (f32x4){0.f, 0.f, 0.f, 0.f};
            acc3[m][n] = (f32x4){0.f, 0.f, 0.f, 0.f};
        }

    auto STAGE = [&](int buf, int k0) {
        bf16* Ab = lds + buf * (LA + 2 * LB);
        bf16* B1b = Ab + LA;
        bf16* B3b = B1b + LB;
        #pragma unroll
        for (int i = 0; i < 4; ++i) {
            int c = wid * 4 + i;
            gload16(A + (size_t)(row0 + c * 8 + srow) * lda + k0 + ssub * 8, Ab + c * 512);
        }
        #pragma unroll
        for (int i = 0; i < 2; ++i) {
            int c = wid * 2 + i;
            gload16(B1t + (size_t)(col0 + c * 8 + srow) * ldb + k0 + ssub * 8, B1b + c * 512);
            gload16(B3t + (size_t)(col0 + c * 8 + srow) * ldb + k0 + ssub * 8, B3b + c * 512);
        }
    };

    const int nt = K >> 6;
    STAGE(0, 0);
    if (nt > 1) STAGE(1, 64);
    for (int t = 0; t < nt; ++t) {
        if (t < nt - 1) wait_vm<8>();
        else            wait_vm<0>();
        __builtin_amdgcn_sched_barrier(0);
        __builtin_amdgcn_s_barrier();
        __builtin_amdgcn_sched_barrier(0);
        const bf16* Ab = lds + (t & 1) * (LA + 2 * LB);
        const bf16* B1b = Ab + LA;
        const bf16* B3b = B1b + LB;
        const int ar = wr * 64 + (lane & 15);
        const int br = wc * 32 + (lane & 15);
        #pragma unroll
        for (int ksel = 0; ksel < 2; ++ksel) {
            const int ps = ((ksel << 2) + (lane >> 4)) ^ (lane & 7);
            bf16x8 af[4], b1f[2], b3f[2];
            #pragma unroll
            for (int m = 0; m < 4; ++m)
                af[m] = *(const bf16x8*)(Ab + (ar + m * 16) * 64 + ps * 8);
            #pragma unroll
            for (int n = 0; n < 2; ++n) {
                b1f[n] = *(const bf16x8*)(B1b + (br + n * 16) * 64 + ps * 8);
                b3f[n] = *(const bf16x8*)(B3b + (br + n * 16) * 64 + ps * 8);
            }
            #pragma unroll
            for (int m = 0; m < 4; ++m)
                #pragma unroll
                for (int n = 0; n < 2; ++n) {
                    acc1[m][n] = __builtin_amdgcn_mfma_f32_16x16x32_bf16(af[m], b1f[n], acc1[m][n], 0, 0, 0);
                    acc3[m][n] = __builtin_amdgcn_mfma_f32_16x16x32_bf16(af[m], b3f[n], acc3[m][n], 0, 0, 0);
                }
        }
        wait_lgkm0();
        __builtin_amdgcn_sched_barrier(0);
        __builtin_amdgcn_s_barrier();
        __builtin_amdgcn_sched_barrier(0);
        if (t + 2 < nt) STAGE(t & 1, (t + 2) << 6);
    }
    const int crow = row0 + wr * 64 + ((lane >> 4) << 2);
    const int ccol = col0 + wc * 32 + (lane & 15);
    #pragma unroll
    for (int m = 0; m < 4; ++m)
        #pragma unroll
        for (int n = 0; n < 2; ++n)
            #pragma unroll
            for (int r = 0; r < 4; ++r) {
                float x = acc1[m][n][r];
                float v = (x * sigm(x)) * acc3[m][n][r];
                Cout[(size_t)(crow + m * 16 + r) * ldc + ccol + n * 16] = (bf16)v;
            }
}

// ============ Fused causal flash attention ============
__global__ __launch_bounds__(256) void flash_attn(
    const bf16* __restrict__ qkv, const bf16* __restrict__ vt,
    bf16* __restrict__ o)
{
    __shared__ bf16 qlds[64 * 64];
    __shared__ bf16 klds[2][64 * 64];
    __shared__ bf16 vlds[2][64 * 64];
    __shared__ bf16 plds[4][16 * 64];
    const int qt = blockIdx.x, hh = blockIdx.y, b = blockIdx.z;
    const int qb0 = qt * 64;
    const int tid = threadIdx.x, wid = tid >> 6, lane = tid & 63;
    const bf16* qg = qkv + (size_t)b * S_ * 3072 + hh * 64;
    const bf16* kg = qg + 1024;
    const bf16* vg = vt + (size_t)(b * H_ + hh) * 64 * 1024;
    const int srow = lane >> 3;
    const int ssub = (lane & 7) ^ (srow & 7);

    #pragma unroll
    for (int i = 0; i < 2; ++i) {
        int c = wid * 2 + i;
        gload16(qg + (size_t)(qb0 + c * 8 + srow) * 3072 + ssub * 8, qlds + c * 512);
    }
    auto STAGE = [&](int buf, int kb) {
        #pragma unroll
        for (int i = 0; i < 2; ++i) {
            int c = wid * 2 + i;
            gload16(kg + (size_t)(kb + c * 8 + srow) * 3072 + ssub * 8, klds[buf] + c * 512);
            gload16(vg + (size_t)(c * 8 + srow) * 1024 + kb + ssub * 8, vlds[buf] + c * 512);
        }
    };

    const int nt = qt + 1;
    STAGE(0, 0);
    if (nt > 1) STAGE(1, 64);

    f32x4 oacc[4];
    #pragma unroll
    for (int n = 0; n < 4; ++n) oacc[n] = (f32x4){0.f, 0.f, 0.f, 0.f};
    float mrow[4] = {-1e30f, -1e30f, -1e30f, -1e30f};
    float lrow[4] = {0.f, 0.f, 0.f, 0.f};
    bf16x8 qf[2];
    bf16* pw = plds[wid];
    const int qlr = (lane >> 4) * 4;

    for (int t = 0; t < nt; ++t) {
        if (t < nt - 1) wait_vm<4>();
        else            wait_vm<0>();
        __builtin_amdgcn_sched_barrier(0);
        __builtin_amdgcn_s_barrier();
        __builtin_amdgcn_sched_barrier(0);
        if (t == 0) {
            const int ar = wid * 16 + (lane & 15);
            #pragma unroll
            for (int ksel = 0; ksel < 2; ++ksel) {
                const int ps = ((ksel << 2) + (lane >> 4)) ^ (lane & 7);
                qf[ksel] = *(const bf16x8*)(qlds + ar * 64 + ps * 8);
            }
        }
        const bf16* Kb = klds[t & 1];
        const bf16* Vb = vlds[t & 1];
        f32x4 sacc[4];
        #pragma unroll
        for (int n = 0; n < 4; ++n) sacc[n] = (f32x4){0.f, 0.f, 0.f, 0.f};
        #pragma unroll
        for (int ksel = 0; ksel < 2; ++ksel) {
            const int ps = ((ksel << 2) + (lane >> 4)) ^ (lane & 7);
            #pragma unroll
            for (int n = 0; n < 4; ++n) {
                bf16x8 kf = *(const bf16x8*)(Kb + (n * 16 + (lane & 15)) * 64 + ps * 8);
                sacc[n] = __builtin_amdgcn_mfma_f32_16x16x32_bf16(qf[ksel], kf, sacc[n], 0, 0, 0);
            }
        }
        if (t == nt - 1) {
            const int qrow = qb0 + wid * 16 + qlr;
            const int kcol = t * 64 + (lane & 15);
            #pragma unroll
            for (int n = 0; n < 4; ++n)
                #pragma unroll
                for (int r = 0; r < 4; ++r)
                    if (kcol + n * 16 > qrow + r) sacc[n][r] = -1e30f;
        }
        #pragma unroll
        for (int r = 0; r < 4; ++r) {
            float mx = fmaxf(fmaxf(sacc[0][r], sacc[1][r]), fmaxf(sacc[2][r], sacc[3][r]));
            #pragma unroll
            for (int off = 8; off > 0; off >>= 1) mx = fmaxf(mx, __shfl_xor(mx, off));
            float mnew = fmaxf(mrow[r], mx);
            float scale = __expf(mrow[r] - mnew);
            float rs = 0.f;
            #pragma unroll
            for (int n = 0; n < 4; ++n) {
                float p = __expf(sacc[n][r] - mnew);
                sacc[n][r] = p;
                rs += p;
            }
            #pragma unroll
            for (int off = 8; off > 0; off >>= 1) rs += __shfl_xor(rs, off);
            lrow[r] = lrow[r] * scale + rs;
            mrow[r] = mnew;
            #pragma unroll
            for (int n = 0; n < 4; ++n) oacc[n][r] *= scale;
        }
        #pragma unroll
        for (int n = 0; n < 4; ++n)
            #pragma unroll
            for (int r = 0; r < 4; ++r) {
                const int qr = qlr + r;
                const int k = n * 16 + (lane & 15);
                const int su = (k >> 3) ^ (qr & 7);
                pw[qr * 64 + su * 8 + (k & 7)] = (bf16)sacc[n][r];
            }
        #pragma unroll
        for (int ksel = 0; ksel < 2; ++ksel) {
            const int ps = ((ksel << 2) + (lane >> 4)) ^ (lane & 7);
            bf16x8 pa = *(const bf16x8*)(pw + (lane & 15) * 64 + ps * 8);
            #pragma unroll
            for (int n = 0; n < 4; ++n) {
                bf16x8 vf = *(const bf16x8*)(Vb + (n * 16 + (lane & 15)) * 64 + ps * 8);
                oacc[n] = __builtin_amdgcn_mfma_f32_16x16x32_bf16(pa, vf, oacc[n], 0, 0, 0);
            }
        }
        wait_lgkm0();
        __builtin_amdgcn_sched_barrier(0);
        __builtin_amdgcn_s_barrier();
        __builtin_amdgcn_sched_barrier(0);
        if (t + 2 < nt) STAGE(t & 1, (t + 2) * 64);
    }
    float inv[4];
    #pragma unroll
    for (int r = 0; r < 4; ++r) inv[r] = 1.f / lrow[r];
    #pragma unroll
    for (int n = 0; n < 4; ++n)
        #pragma unroll
        for (int r = 0; r < 4; ++r) {
            const int q = qb0 + wid * 16 + qlr + r;
            const int d = n * 16 + (lane & 15);
            o[(size_t)(b * S_ + q) * 1024 + hh * 64 + d] = (bf16)(oacc[n][r] * inv[r]);
        }
}

// ============ single mega transpose-cast: all weights ============
struct TCD { const float* src; bf16* dst; int ct; int rt; int start; };
struct TCA { TCD e[12]; };
__global__ __launch_bounds__(256) void tcast_all(TCA p)
{
    __shared__ float t[32][33];
    const int flat = blockIdx.x;
    int i = 0;
    #pragma unroll
    for (int j = 1; j < 12; ++j) if (flat >= p.e[j].start) i = j;
    const TCD d = p.e[i];
    const int local = flat - d.start;
    const int cx = local % d.ct, ry = local / d.ct;
    const int C = d.ct * 32, R = d.rt * 32;
    const int c0 = cx * 32, r0 = ry * 32;
    const int tx = threadIdx.x & 31, ty = threadIdx.x >> 5;
    #pragma unroll
    for (int j = 0; j < 4; ++j)
        t[ty + j * 8][tx] = d.src[(size_t)(r0 + ty + j * 8) * C + c0 + tx];
    __syncthreads();
    #pragma unroll
    for (int j = 0; j < 4; ++j)
        d.dst[(size_t)(c0 + ty + j * 8) * R + r0 + tx] = (bf16)t[tx][ty + j * 8];
}

// ============ RMSNorm -> bf16 out ============
__global__ __launch_bounds__(256) void rmsnorm_bf(
    const float* __restrict__ x, const float* __restrict__ w, bf16* __restrict__ out)
{
    __shared__ float red[4];
    const int row = blockIdx.x, tid = threadIdx.x;
    const float* xr = x + (size_t)row * D_;
    f32x4 v = *(const f32x4*)(xr + tid * 4);
    float ss = v.x * v.x + v.y * v.y + v.z * v.z + v.w * v.w;
    #pragma unroll
    for (int off = 32; off > 0; off >>= 1) ss += __shfl_xor(ss, off);
    if ((tid & 63) == 0) red[tid >> 6] = ss;
    __syncthreads();
    float scn = rsqrtf((red[0] + red[1] + red[2] + red[3]) * (1.f / D_) + 1e-6f);
    f32x4 wv = *(const f32x4*)(w + tid * 4);
    bf16x4 o;
    o[0] = (bf16)(v.x * scn * wv.x); o[1] = (bf16)(v.y * scn * wv.y);
    o[2] = (bf16)(v.z * scn * wv.z); o[3] = (bf16)(v.w * scn * wv.w);
    *(bf16x4*)(out + (size_t)row * D_ + tid * 4) = o;
}

// ============ Fused h1 postlude: strength GEMV + rmsnorm(h1, nmw) ============
__global__ __launch_bounds__(256) void h1_post(
    const float* __restrict__ h1, const float* __restrict__ nmw,
    const float* __restrict__ wst, bf16* __restrict__ nbf, float* __restrict__ stb)
{
    __shared__ float red[4], red2[4];
    const int row = blockIdx.x, tid = threadIdx.x;
    const float* xr = h1 + (size_t)row * D_;
    f32x4 v = *(const f32x4*)(xr + tid * 4);
    f32x4 wv = *(const f32x4*)(wst + tid * 4);
    float ss = v.x * v.x + v.y * v.y + v.z * v.z + v.w * v.w;
    float dt = v.x * wv.x + v.y * wv.y + v.z * wv.z + v.w * wv.w;
    #pragma unroll
    for (int off = 32; off > 0; off >>= 1) {
        ss += __shfl_xor(ss, off);
        dt += __shfl_xor(dt, off);
    }
    if ((tid & 63) == 0) { red[tid >> 6] = ss; red2[tid >> 6] = dt; }
    __syncthreads();
    float scn = rsqrtf((red[0] + red[1] + red[2] + red[3]) * (1.f / D_) + 1e-6f);
    f32x4 nw = *(const f32x4*)(nmw + tid * 4);
    bf16x4 o;
    o[0] = (bf16)(v.x * scn * nw.x); o[1] = (bf16)(v.y * scn * nw.y);
    o[2] = (bf16)(v.z * scn * nw.z); o[3] = (bf16)(v.w * scn * nw.w);
    *(bf16x4*)(nbf + (size_t)row * D_ + tid * 4) = o;
    if (tid == 0) stb[row] = sigm(red2[0] + red2[1] + red2[2] + red2[3]);
}

// ============ Fused RoPE (q,k in-place) + V^T staging ============
__global__ __launch_bounds__(256) void rope_vt(
    bf16* __restrict__ qkv, const float* __restrict__ cosp,
    const float* __restrict__ sinp, bf16* __restrict__ vt)
{
    __shared__ bf16 vl[64][72];
    const int st = blockIdx.x, hh = blockIdx.y, b = blockIdx.z;
    const int tid = threadIdx.x;
    const int r = tid >> 2;
    const int p0 = (tid & 3) * 8;
    const int s = st * 64 + r;
    bf16* base = qkv + ((size_t)(b * S_ + s)) * 3072 + hh * 64;
    {
        f32x4 c1a = *(const f32x4*)(cosp + s * 64 + p0);
        f32x4 c1b = *(const f32x4*)(cosp + s * 64 + p0 + 4);
        f32x4 s1a = *(const f32x4*)(sinp + s * 64 + p0);
        f32x4 s1b = *(const f32x4*)(sinp + s * 64 + p0 + 4);
        f32x4 c2a = *(const f32x4*)(cosp + s * 64 + p0 + 32);
        f32x4 c2b = *(const f32x4*)(cosp + s * 64 + p0 + 36);
        f32x4 s2a = *(const f32x4*)(sinp + s * 64 + p0 + 32);
        f32x4 s2b = *(const f32x4*)(sinp + s * 64 + p0 + 36);
        float c1[8] = {c1a.x,c1a.y,c1a.z,c1a.w,c1b.x,c1b.y,c1b.z,c1b.w};
        float s1[8] = {s1a.x,s1a.y,s1a.z,s1a.w,s1b.x,s1b.y,s1b.z,s1b.w};
        float c2[8] = {c2a.x,c2a.y,c2a.z,c2a.w,c2b.x,c2b.y,c2b.z,c2b.w};
        float s2[8] = {s2a.x,s2a.y,s2a.z,s2a.w,s2b.x,s2b.y,s2b.z,s2b.w};
        #pragma unroll
        for (int which = 0; which < 2; ++which) {
            bf16* ptr = base + which * 1024;
            bf16x8 x1 = *(const bf16x8*)(ptr + p0);
            bf16x8 x2 = *(const bf16x8*)(ptr + p0 + 32);
            bf16x8 o1, o2;
            float qs = which ? 1.f : 0.125f;
            #pragma unroll
            for (int j = 0; j < 8; ++j) {
                float a = (float)x1[j], bb = (float)x2[j];
                o1[j] = (bf16)((a * c1[j] - bb * s1[j]) * qs);
                o2[j] = (bf16)((bb * c2[j] + a * s2[j]) * qs);
            }
            *(bf16x8*)(ptr + p0) = o1;
            *(bf16x8*)(ptr + p0 + 32) = o2;
        }
    }
    {
        const int d0 = (tid & 3) * 16;
        bf16x8 v0 = *(const bf16x8*)(base + 2048 + d0);
        bf16x8 v1 = *(const bf16x8*)(base + 2048 + d0 + 8);
        #pragma unroll
        for (int j = 0; j < 8; ++j) { vl[r][d0 + j] = v0[j]; vl[r][d0 + 8 + j] = v1[j]; }
    }
    __syncthreads();
    {
        const int d = tid >> 2;
        const int sq = (tid & 3) * 16;
        bf16x8 o0, o1;
        #pragma unroll
        for (int j = 0; j < 8; ++j) { o0[j] = vl[sq + j][d]; o1[j] = vl[sq + 8 + j][d]; }
        bf16* dst = vt + (size_t)(b * H_ + hh) * 65536 + (size_t)d * 1024 + st * 64 + sq;
        *(bf16x8*)(dst) = o0;
        *(bf16x8*)(dst + 8) = o1;
    }
}

// ============ memory softmax: bf16 [row][2048] -> bf16 probs, scale 1/16 ============
__global__ __launch_bounds__(256) void mem_softmax(
    const bf16* __restrict__ ms, bf16* __restrict__ out)
{
    __shared__ float red[4];
    const int row = blockIdx.x, tid = threadIdx.x;
    bf16x8 iv = *(const bf16x8*)(ms + (size_t)row * 2048 + tid * 8);
    float xs[8];
    float mx = -1e30f;
    #pragma unroll
    for (int i = 0; i < 8; ++i) { xs[i] = (float)iv[i]; mx = fmaxf(mx, xs[i]); }
    #pragma unroll
    for (int off = 32; off > 0; off >>= 1) mx = fmaxf(mx, __shfl_xor(mx, off));
    if ((tid & 63) == 0) red[tid >> 6] = mx;
    __syncthreads();
    mx = fmaxf(fmaxf(red[0], red[1]), fmaxf(red[2], red[3]));
    __syncthreads();
    float sum = 0.f;
    #pragma unroll
    for (int i = 0; i < 8; ++i) { xs[i] = __expf((xs[i] - mx) * 0.0625f); sum += xs[i]; }
    #pragma unroll
    for (int off = 32; off > 0; off >>= 1) sum += __shfl_xor(sum, off);
    if ((tid & 63) == 0) red[tid >> 6] = sum;
    __syncthreads();
    float inv = 1.f / (red[0] + red[1] + red[2] + red[3]);
    bf16x8 o;
    #pragma unroll
    for (int i = 0; i < 8; ++i) o[i] = (bf16)(xs[i] * inv);
    *(bf16x8*)(out + (size_t)row * 2048 + tid * 8) = o;
}

// ============ memory update + new_values^T in one pass ============
__global__ __launch_bounds__(256) void mem_upd2(
    const bf16* __restrict__ ctcp, const float* __restrict__ st,
    const float* __restrict__ memk, const float* __restrict__ memv,
    const int* __restrict__ pos,
    float* __restrict__ outk, float* __restrict__ outv,
    bf16* __restrict__ okbf, bf16* __restrict__ nvt)
{
    __shared__ float tl[64][65];
    const int dt = blockIdx.x, mt = blockIdx.y, b = blockIdx.z;
    const int tid = threadIdx.x;
    const int r = tid >> 2, q = tid & 3;
    const int m = mt * 64 + r;
    int s = (m - pos[0]) % M_; if (s < 0) s += M_;
    const bool upd = (s < S_);
    const float t = upd ? st[b * S_ + s] : 0.f;
    float res[16];
    if (dt < 16) {
        const int c0 = dt * 64 + q * 16;
        size_t vi = ((size_t)b * M_ + m) * D_ + c0;
        #pragma unroll
        for (int j = 0; j < 4; ++j) {
            f32x4 o = *(const f32x4*)(memv + vi + j * 4);
            res[4*j] = o.x; res[4*j+1] = o.y; res[4*j+2] = o.z; res[4*j+3] = o.w;
        }
        if (upd) {
            const bf16* cp = ctcp + ((size_t)(b * S_ + s)) * 1280 + c0;
            bf16x8 ca = *(const bf16x8*)cp;
            bf16x8 cb = *(const bf16x8*)(cp + 8);
            #pragma unroll
            for (int j = 0; j < 8; ++j) {
                res[j]     = t * (float)ca[j] + (1.f - t) * res[j];
                res[8 + j] = t * (float)cb[j] + (1.f - t) * res[8 + j];
            }
        }
        #pragma unroll
        for (int j = 0; j < 4; ++j) {
            f32x4 o = {res[4*j], res[4*j+1], res[4*j+2], res[4*j+3]};
            *(f32x4*)(outv + vi + j * 4) = o;
        }
        #pragma unroll
        for (int j = 0; j < 16; ++j) tl[r][q * 16 + j] = res[j];
        __syncthreads();
        const int rd = tid >> 2;
        bf16x8 oa, ob;
        #pragma unroll
        for (int j = 0; j < 8; ++j) {
            oa[j] = (bf16)tl[q * 16 + j][rd];
            ob[j] = (bf16)tl[q * 16 + 8 + j][rd];
        }
        bf16* dst = nvt + (size_t)b * 1024 * 2048 + (size_t)(dt * 64 + rd) * 2048 + mt * 64 + q * 16;
        *(bf16x8*)dst = oa;
        *(bf16x8*)(dst + 8) = ob;
    } else {
        const int c0 = (dt - 16) * 64 + q * 16;
        size_t ki = ((size_t)b * M_ + m) * DC_ + c0;
        #pragma unroll
        for (int j = 0; j < 4; ++j) {
            f32x4 o = *(const f32x4*)(memk + ki + j * 4);
            res[4*j] = o.x; res[4*j+1] = o.y; res[4*j+2] = o.z; res[4*j+3] = o.w;
        }
        if (upd) {
            const bf16* cp = ctcp + ((size_t)(b * S_ + s)) * 1280 + 1024 + c0;
            bf16x8 ca = *(const bf16x8*)cp;
            bf16x8 cb = *(const bf16x8*)(cp + 8);
            #pragma unroll
            for (int j = 0; j < 8; ++j) {
                res[j]     = t * (float)ca[j] + (1.f - t) * res[j];
                res[8 + j] = t * (float)cb[j] + (1.f - t) * res[8 + j];
            }
        }
        bf16x8 oa, ob;
        #pragma unroll
        for (int j = 0; j < 4; ++j) {
            f32x4 o = {res[4*j], res[4*j+1], res[4*j+2], res[4*j+3]};
            *(f32x4*)(outk + ki + j * 4) = o;
        }
        #pragma unroll
        for (int j = 0; j < 8; ++j) { oa[j] = (bf16)res[j]; ob[j] = (bf16)res[8 + j]; }
        *(bf16x8*)(okbf + ki) = oa;
        *(bf16x8*)(okbf + ki + 8) = ob;
    }
}

extern "C" void kernel_launch(void* const* d_in, const int* in_sizes, int n_in,
                              void* d_out, int out_size, void* d_ws, size_t ws_size,
                              hipStream_t stream)
{
    const float* h0   = (const float*)d_in[0];
    const float* memk = (const float*)d_in[1];
    const float* memv = (const float*)d_in[2];
    const float* cosp = (const float*)d_in[3];
    const float* sinp = (const float*)d_in[4];
    const float* n1w  = (const float*)d_in[5];
    const float* n2w  = (const float*)d_in[6];
    const float* nmw  = (const float*)d_in[7];
    const float* Wq   = (const float*)d_in[8];
    const float* Wk   = (const float*)d_in[9];
    const float* Wv   = (const float*)d_in[10];
    const float* Wo   = (const float*)d_in[11];
    const float* Wct  = (const float*)d_in[12];
    const float* Wcp  = (const float*)d_in[13];
    const float* Wst  = (const float*)d_in[14];
    const float* Wqr  = (const float*)d_in[15];
    const float* Wg   = (const float*)d_in[16];
    const float* Wpj  = (const float*)d_in[17];
    const float* W1   = (const float*)d_in[18];
    const float* W3   = (const float*)d_in[19];
    const float* W2   = (const float*)d_in[20];
    const int*   pos  = (const int*)d_in[21];

    float* out_h = (float*)d_out;
    float* out_k = out_h + (size_t)NTOK * D_;
    float* out_v = out_k + (size_t)B_ * M_ * DC_;

    char* W = (char*)d_ws;
    const size_t MB = 1u << 20;
    bf16*  qkvb = (bf16*)(W);               // 0..12 MB [2048][3072]
    bf16*  vtb  = (bf16*)(W + 12 * MB);     // 12..16 V^T
    bf16*  nbf  = (bf16*)(W + 16 * MB);     // 16..20 rmsnorm out
    bf16*  abf  = (bf16*)(W + 20 * MB);     // 20..24 attn out
    float* h1b  = (float*)(W + 24 * MB);    // 24..32
    bf16*  catbf= (bf16*)(W + 32 * MB);     // 32..40 [2048][2048] = [h1bf | retr]
    bf16*  ctcp = (bf16*)(W + 40 * MB);     // 40..45 bf16 [2048][1280]
    float* stb  = (float*)(W + 51 * MB);    // 8 KB
    bf16*  msbf = (bf16*)(W + 52 * MB);     // 52..60 mem scores bf16
    bf16*  matt = (bf16*)(W + 68 * MB);     // 68..76 mem probs
    bf16*  nvt  = (bf16*)(W + 76 * MB);     // 76..84 new_values^T
    bf16*  a1bf = (bf16*)(W);               // 0..16 MLP act (overlays qkvb+vtb)
    bf16*  okbf = (bf16*)(W + 84 * MB);     // 84..86
    bf16*  qmbf = (bf16*)(W + 86 * MB);     // 86..87
    float* h2b  = (float*)(W + 96 * MB);    // 96..104
    bf16*  WqkvT= (bf16*)(W + 104 * MB);    // 104..110
    bf16*  WoT  = (bf16*)(W + 110 * MB);    // 110..112
    bf16*  WctcpT=(bf16*)(W + 112 * MB);    // 112..114.5
    bf16*  WqrT = (bf16*)(W + 115 * MB);    // 115..115.5
    bf16*  WgT  = (bf16*)(W + 116 * MB);    // 116..120
    bf16*  WpjT = (bf16*)(W + 120 * MB);    // 120..122
    bf16*  W13T = (bf16*)(W + 122 * MB);    // 122..138
    bf16*  W2T  = (bf16*)(W + 138 * MB);    // 138..146

    // ---- single mega weight transpose-cast ----
    {
        TCA p;
        auto set = [&](int i, const float* s, bf16* d, int ct, int rt, int st_) {
            p.e[i].src = s; p.e[i].dst = d; p.e[i].ct = ct; p.e[i].rt = rt; p.e[i].start = st_;
        };
        int off = 0;
        set(0,  Wq,  WqkvT,               32, 32,  off); off += 1024;
        set(1,  Wk,  WqkvT + 1024 * 1024, 32, 32,  off); off += 1024;
        set(2,  Wv,  WqkvT + 2048 * 1024, 32, 32,  off); off += 1024;
        set(3,  Wo,  WoT,                 32, 32,  off); off += 1024;
        set(4,  Wct, WctcpT,              32, 32,  off); off += 1024;
        set(5,  Wpj, WpjT,                32, 32,  off); off += 1024;
        set(6,  Wcp, WctcpT + 1024 * 1024, 8, 32,  off); off += 256;
        set(7,  Wqr, WqrT,                 8, 32,  off); off += 256;
        set(8,  Wg,  WgT,                 32, 64,  off); off += 2048;
        set(9,  W1,  W13T,               128, 32,  off); off += 4096;
        set(10, W3,  W13T + 4096 * 1024, 128, 32,  off); off += 4096;
        set(11, W2,  W2T,                 32, 128, off); off += 4096;
        tcast_all<<<off, 256, 0, stream>>>(p);
    }

    // ---- 1. rmsnorm; QKV; fused RoPE + V^T ----
    rmsnorm_bf<<<NTOK, 256, 0, stream>>>(h0, n1w, nbf);
    mgemm<64, 128, true, 0><<<dim3(24, 32, 1), 256, 0, stream>>>(
        nbf, WqkvT, nullptr, qkvb, 1024, 1024, 1024, 3072, 0, 0, 0, nullptr);
    rope_vt<<<dim3(S_ / 64, H_, B_), 256, 0, stream>>>(qkvb, cosp, sinp, vtb);

    // ---- 2. fused causal flash attention ----
    flash_attn<<<dim3(S_ / 64, H_, B_), 256, 0, stream>>>(qkvb, vtb, abf);

    // ---- 3. h1 = h0 + attn @ Wo (dual write) + fused strength/rmsnorm ----
    mgemm<64, 64, false, 1><<<dim3(16, 32, 1), 256, 0, stream>>>(
        abf, WoT, h0, h1b, 1024, 1024, 1024, 1024, 0, 0, 0, catbf);
    h1_post<<<NTOK, 256, 0, stream>>>(h1b, nmw, Wst, nbf, stb);

    // ---- 4. content|compressed (bf16); memory update + nvt ----
    mgemm<64, 64, true, 0><<<dim3(20, 32, 1), 256, 0, stream>>>(
        catbf, WctcpT, nullptr, ctcp, 1024, 2048, 1024, 1280, 0, 0, 0, nullptr);
    mem_upd2<<<dim3(20, 32, 2), 256, 0, stream>>>(
        ctcp, stb, memk, memv, pos, out_k, out_v, okbf, nvt);

    // ---- 5. memory attention ----
    mgemm<64, 64, true, 0><<<dim3(4, 32, 1), 256, 0, stream>>>(
        nbf, WqrT, nullptr, qmbf, 1024, 1024, 1024, 256, 0, 0, 0, nullptr);
    mgemm<64, 128, true, 0><<<dim3(16, 16, 2), 256, 0, stream>>>(
        qmbf, okbf, nullptr, msbf, 256, 256, 256, 2048,
        (long long)S_ * 256, (long long)M_ * 256, (long long)S_ * 2048, nullptr);
    mem_softmax<<<NTOK, 256, 0, stream>>>(msbf, matt);
    mgemm<64, 64, true, 0><<<dim3(16, 16, 2), 256, 0, stream>>>(
        matt, nvt, nullptr, catbf + 1024, 2048, 2048, 2048, 2048,
        (long long)S_ * 2048, (long long)1024 * 2048, (long long)S_ * 2048, nullptr);

    // ---- 6. merged gate+proj GEMM; dual-writes h2b AND out_h prefill ----
    mgemm_gp<<<dim3(16, 32, 1), 256, 0, stream>>>(catbf, WgT, WpjT, h1b, h2b, out_h);

    // ---- 7. MLP: up+silu-mul, then split-K=2 down via atomicAdd into out_h ----
    rmsnorm_bf<<<NTOK, 256, 0, stream>>>(h2b, n2w, nbf);
    mgemm13<<<dim3(64, 16, 1), 256, 0, stream>>>(
        nbf, W13T, W13T + 4096 * 1024, a1bf, 1024, 1024, 1024, 4096);
    mgemm<64, 64, false, 3><<<dim3(16, 32, 2), 256, 0, stream>>>(
        a1bf, W2T, nullptr, out_h, 2048, 4096, 4096, 1024, 2048, 2048, 0, nullptr);
}